// Round 11
// baseline (327.410 us; speedup 1.0000x reference)
//
#include <hip/hip_runtime.h>

// Problem constants (from reference)
constexpr int N  = 50000;   // nodes
constexpr int E  = 800000;  // edges
constexpr int C  = 128;     // feature dim (IN_C == HID)
constexpr int G  = 256;     // graphs
constexpr int OC = 64;      // out channels
constexpr int D  = 64;      // ELL padded degree (Poisson(16): P(deg>=64) ~ 1e-20)

typedef __attribute__((ext_vector_type(8))) short short8;
typedef __attribute__((ext_vector_type(4))) float f32x4;
typedef __attribute__((ext_vector_type(2))) float f32x2;

__device__ __forceinline__ unsigned int au(float f) { return __float_as_uint(f); }

__device__ __forceinline__ unsigned short f2bf(float f) {
    unsigned int u = au(f);
    u += 0x7fffu + ((u >> 16) & 1u);   // round-to-nearest-even
    return (unsigned short)(u >> 16);
}
// pack two floats to bf16x2 with round-half-up (cheap, bias negligible)
__device__ __forceinline__ unsigned int pack_bf16(float lo, float hi) {
    return ((au(hi) + 0x8000u) & 0xFFFF0000u) | ((au(lo) + 0x8000u) >> 16);
}

// decode 16 fp8(e4m3) in uint4 -> accumulate into 8 float2 (HW converts, pk adds)
__device__ __forceinline__ void acc16(f32x2* a, uint4 v) {
    a[0] += __builtin_amdgcn_cvt_pk_f32_fp8((int)v.x, false);
    a[1] += __builtin_amdgcn_cvt_pk_f32_fp8((int)v.x, true);
    a[2] += __builtin_amdgcn_cvt_pk_f32_fp8((int)v.y, false);
    a[3] += __builtin_amdgcn_cvt_pk_f32_fp8((int)v.y, true);
    a[4] += __builtin_amdgcn_cvt_pk_f32_fp8((int)v.z, false);
    a[5] += __builtin_amdgcn_cvt_pk_f32_fp8((int)v.z, true);
    a[6] += __builtin_amdgcn_cvt_pk_f32_fp8((int)v.w, false);
    a[7] += __builtin_amdgcn_cvt_pk_f32_fp8((int)v.w, true);
}
__device__ __forceinline__ void set16(f32x2* a, uint4 v) {
    a[0] = __builtin_amdgcn_cvt_pk_f32_fp8((int)v.x, false);
    a[1] = __builtin_amdgcn_cvt_pk_f32_fp8((int)v.x, true);
    a[2] = __builtin_amdgcn_cvt_pk_f32_fp8((int)v.y, false);
    a[3] = __builtin_amdgcn_cvt_pk_f32_fp8((int)v.y, true);
    a[4] = __builtin_amdgcn_cvt_pk_f32_fp8((int)v.z, false);
    a[5] = __builtin_amdgcn_cvt_pk_f32_fp8((int)v.z, true);
    a[6] = __builtin_amdgcn_cvt_pk_f32_fp8((int)v.w, false);
    a[7] = __builtin_amdgcn_cvt_pk_f32_fp8((int)v.w, true);
}

// ---------------- ELL build: COLUMN-MAJOR ell[p*N + dst] ----------------

__global__ __launch_bounds__(256) void ell_build_kernel(const int* __restrict__ src,
                                                        const int* __restrict__ dst,
                                                        int* __restrict__ cursor,
                                                        unsigned short* __restrict__ ell) {
    int t = blockIdx.x * 256 + threadIdx.x;
    int e0 = t * 4;
    if (e0 + 4 <= E) {
        int4 d4 = ((const int4*)dst)[t];
        int4 s4 = ((const int4*)src)[t];
        int p0 = atomicAdd(&cursor[d4.x], 1);
        int p1 = atomicAdd(&cursor[d4.y], 1);
        int p2 = atomicAdd(&cursor[d4.z], 1);
        int p3 = atomicAdd(&cursor[d4.w], 1);
        if (p0 < D) ell[(size_t)p0 * N + d4.x] = (unsigned short)s4.x;
        if (p1 < D) ell[(size_t)p1 * N + d4.y] = (unsigned short)s4.y;
        if (p2 < D) ell[(size_t)p2 * N + d4.z] = (unsigned short)s4.z;
        if (p3 < D) ell[(size_t)p3 * N + d4.w] = (unsigned short)s4.w;
    } else {
        for (int e = e0; e < E; ++e) {
            int d = dst[e];
            int p = atomicAdd(&cursor[d], 1);
            if (p < D) ell[(size_t)p * N + d] = (unsigned short)src[e];
        }
    }
}

// ---------------- prep: weights -> bf16 WT[n][k]; x -> fp8 table ----------------

__global__ __launch_bounds__(256) void prep_kernel(const float* __restrict__ W1a,
                                                   const float* __restrict__ W1b,
                                                   const float* __restrict__ W2a,
                                                   const float* __restrict__ W2b,
                                                   const float* __restrict__ x,
                                                   unsigned short* __restrict__ wt,
                                                   unsigned int* __restrict__ x8) {
    int b = blockIdx.x;
    if (b < 256) {
        const float* Ws[4] = {W1a, W1b, W2a, W2b};
        int idx = b * 256 + threadIdx.x;   // < 65536
        int which = idx >> 14;
        int el    = idx & 16383;
        int n = el >> 7, k = el & 127;
        wt[idx] = f2bf(Ws[which][k * 128 + n]);
    } else {
        int idx = (b - 256) * 256 + threadIdx.x;   // < N*C/8 = 800000
        const float4* x4 = (const float4*)x;
        float4 v0 = x4[idx * 2];
        float4 v1 = x4[idx * 2 + 1];
        unsigned int lo = 0, hi = 0;
        lo = (unsigned int)__builtin_amdgcn_cvt_pk_fp8_f32(v0.x, v0.y, (int)lo, false);
        lo = (unsigned int)__builtin_amdgcn_cvt_pk_fp8_f32(v0.z, v0.w, (int)lo, true);
        hi = (unsigned int)__builtin_amdgcn_cvt_pk_fp8_f32(v1.x, v1.y, (int)hi, false);
        hi = (unsigned int)__builtin_amdgcn_cvt_pk_fp8_f32(v1.z, v1.w, (int)hi, true);
        ((uint2*)x8)[idx] = make_uint2(lo, hi);
    }
}

// ---------------- aggregate: Y[n] = F[n] + sum_nb F[j]  (fp8 in, bf16 out) ----------------
// Zero LDS, 8 lanes/node (uint4 = 16 fp8 ch each). Software-pipelined batch-8:
// decode batch k while batch k+1's index+row loads are in flight.

__global__ __launch_bounds__(256) void aggregate_kernel(const unsigned char* __restrict__ Fg,
                                                        const int* __restrict__ deg,
                                                        const unsigned short* __restrict__ ell,
                                                        unsigned short* __restrict__ Y) {
    int grp = threadIdx.x >> 3;   // 0..31
    int l   = threadIdx.x & 7;    // 0..7
    int n = blockIdx.x * 32 + grp;
    if (n >= N) return;
    const uint4* F16 = (const uint4*)Fg;
    f32x2 a[8];
    int dg = min(deg[n], D);
    const unsigned short* ecol = ell + n;   // slot p at ecol[p*N]
    set16(a, F16[(size_t)n * 8 + l]);       // self
    int j = 0;
    if (dg >= 8) {
        int i0 = ecol[0];
        int i1 = ecol[(size_t)1 * N];
        int i2 = ecol[(size_t)2 * N];
        int i3 = ecol[(size_t)3 * N];
        int i4 = ecol[(size_t)4 * N];
        int i5 = ecol[(size_t)5 * N];
        int i6 = ecol[(size_t)6 * N];
        int i7 = ecol[(size_t)7 * N];
        uint4 v0 = F16[(size_t)i0 * 8 + l];
        uint4 v1 = F16[(size_t)i1 * 8 + l];
        uint4 v2 = F16[(size_t)i2 * 8 + l];
        uint4 v3 = F16[(size_t)i3 * 8 + l];
        uint4 v4 = F16[(size_t)i4 * 8 + l];
        uint4 v5 = F16[(size_t)i5 * 8 + l];
        uint4 v6 = F16[(size_t)i6 * 8 + l];
        uint4 v7 = F16[(size_t)i7 * 8 + l];
        for (j = 8; j + 8 <= dg; j += 8) {
            int t0 = ecol[(size_t)(j + 0) * N];
            int t1 = ecol[(size_t)(j + 1) * N];
            int t2 = ecol[(size_t)(j + 2) * N];
            int t3 = ecol[(size_t)(j + 3) * N];
            int t4 = ecol[(size_t)(j + 4) * N];
            int t5 = ecol[(size_t)(j + 5) * N];
            int t6 = ecol[(size_t)(j + 6) * N];
            int t7 = ecol[(size_t)(j + 7) * N];
            uint4 w0 = F16[(size_t)t0 * 8 + l];
            uint4 w1 = F16[(size_t)t1 * 8 + l];
            uint4 w2 = F16[(size_t)t2 * 8 + l];
            uint4 w3 = F16[(size_t)t3 * 8 + l];
            uint4 w4 = F16[(size_t)t4 * 8 + l];
            uint4 w5 = F16[(size_t)t5 * 8 + l];
            uint4 w6 = F16[(size_t)t6 * 8 + l];
            uint4 w7 = F16[(size_t)t7 * 8 + l];
            // decode previous batch while w* are in flight
            acc16(a, v0); acc16(a, v1); acc16(a, v2); acc16(a, v3);
            acc16(a, v4); acc16(a, v5); acc16(a, v6); acc16(a, v7);
            v0 = w0; v1 = w1; v2 = w2; v3 = w3;
            v4 = w4; v5 = w5; v6 = w6; v7 = w7;
        }
        acc16(a, v0); acc16(a, v1); acc16(a, v2); acc16(a, v3);
        acc16(a, v4); acc16(a, v5); acc16(a, v6); acc16(a, v7);
    }
    for (; j < dg; ++j) {
        uint4 v = F16[(size_t)ecol[(size_t)j * N] * 8 + l];
        acc16(a, v);
    }
    uint4 o0, o1;
    o0.x = pack_bf16(a[0].x, a[0].y); o0.y = pack_bf16(a[1].x, a[1].y);
    o0.z = pack_bf16(a[2].x, a[2].y); o0.w = pack_bf16(a[3].x, a[3].y);
    o1.x = pack_bf16(a[4].x, a[4].y); o1.y = pack_bf16(a[5].x, a[5].y);
    o1.z = pack_bf16(a[6].x, a[6].y); o1.w = pack_bf16(a[7].x, a[7].y);
    uint4* yp = (uint4*)(Y + (size_t)n * 128 + l * 16);
    yp[0] = o0;
    yp[1] = o1;
}

// ---------------- MLP: H = relu(X@Wa + ba)@Wb + bb  (bf16 MFMA) ----------------
// outFp8=1: write fp8 table (conv1). outFp8=0: fused mean-pool accumulate (conv2):
// per-graph LDS reduction (batch sorted -> 1-2 graphs per 64-row tile) + global atomics.

__global__ __launch_bounds__(256) void mlp_kernel(const unsigned short* __restrict__ Xg,
                                                  const unsigned short* __restrict__ WaT,
                                                  const float* __restrict__ ba,
                                                  const unsigned short* __restrict__ WbT,
                                                  const float* __restrict__ bb,
                                                  unsigned char* __restrict__ Hg8,
                                                  const int* __restrict__ batch,
                                                  float* __restrict__ gsum,
                                                  int* __restrict__ gcnt,
                                                  int outFp8) {
    constexpr int LD = 136;  // padded row stride in halfs
    __shared__ short Xl[64 * LD];
    __shared__ short Wl[128 * LD];
    __shared__ int   bgr[64];
    __shared__ float lsum[128];
    int tid  = threadIdx.x;
    int lane = tid & 63;
    int wave = tid >> 6;
    int row0 = blockIdx.x * 64;

    // stage X tile (y is padded past N rows, no guard needed)
    const short8* Xg8 = (const short8*)(Xg + (size_t)row0 * 128);
#pragma unroll
    for (int i = tid; i < 1024; i += 256) {
        int r = i >> 4, c = i & 15;
        *((short8*)(Xl + r * LD) + c) = Xg8[i];
    }
    const short8* Wa8 = (const short8*)WaT;
#pragma unroll
    for (int i = tid; i < 2048; i += 256) {
        int r = i >> 4, c = i & 15;
        *((short8*)(Wl + r * LD) + c) = Wa8[i];
    }
    if (!outFp8 && tid < 64) {
        int row = row0 + tid;
        int g = (row < N) ? batch[row] : -1;
        bgr[tid] = g;
        if (g >= 0) atomicAdd(&gcnt[g], 1);
    }

    int mw = wave >> 1, nw = wave & 1;
    int lid = lane & 15, quad = lane >> 4;

    f32x4 acc[2][4];
#pragma unroll
    for (int nt = 0; nt < 4; ++nt) {
        float b = ba[nw * 64 + nt * 16 + lid];
        acc[0][nt] = (f32x4){b, b, b, b};
        acc[1][nt] = (f32x4){b, b, b, b};
    }
    __syncthreads();

    // layer 1: T = relu(X @ Wa + ba)
#pragma unroll
    for (int ks = 0; ks < 4; ++ks) {
        short8 a0 = *(const short8*)(Xl + (mw * 32 + lid) * LD + ks * 32 + quad * 8);
        short8 a1 = *(const short8*)(Xl + (mw * 32 + 16 + lid) * LD + ks * 32 + quad * 8);
#pragma unroll
        for (int nt = 0; nt < 4; ++nt) {
            short8 bf = *(const short8*)(Wl + (nw * 64 + nt * 16 + lid) * LD + ks * 32 + quad * 8);
            acc[0][nt] = __builtin_amdgcn_mfma_f32_16x16x32_bf16(a0, bf, acc[0][nt], 0, 0, 0);
            acc[1][nt] = __builtin_amdgcn_mfma_f32_16x16x32_bf16(a1, bf, acc[1][nt], 0, 0, 0);
        }
    }
    __syncthreads();

    // write T (relu, bf16) over the X tile; D-frag: row = quad*4+r, col = lid
#pragma unroll
    for (int mt = 0; mt < 2; ++mt) {
#pragma unroll
        for (int nt = 0; nt < 4; ++nt) {
            int mbase = mw * 32 + mt * 16 + quad * 4;
            int n = nw * 64 + nt * 16 + lid;
            f32x4 v = acc[mt][nt];
#pragma unroll
            for (int r = 0; r < 4; ++r)
                Xl[(mbase + r) * LD + n] = (short)f2bf(fmaxf(v[r], 0.f));
        }
    }
    const short8* Wb8 = (const short8*)WbT;
#pragma unroll
    for (int i = tid; i < 2048; i += 256) {
        int r = i >> 4, c = i & 15;
        *((short8*)(Wl + r * LD) + c) = Wb8[i];
    }
    f32x4 acc2[2][4];
#pragma unroll
    for (int nt = 0; nt < 4; ++nt) {
        float b = bb[nw * 64 + nt * 16 + lid];
        acc2[0][nt] = (f32x4){b, b, b, b};
        acc2[1][nt] = (f32x4){b, b, b, b};
    }
    __syncthreads();

    // layer 2: H = T @ Wb + bb
#pragma unroll
    for (int ks = 0; ks < 4; ++ks) {
        short8 a0 = *(const short8*)(Xl + (mw * 32 + lid) * LD + ks * 32 + quad * 8);
        short8 a1 = *(const short8*)(Xl + (mw * 32 + 16 + lid) * LD + ks * 32 + quad * 8);
#pragma unroll
        for (int nt = 0; nt < 4; ++nt) {
            short8 bf = *(const short8*)(Wl + (nw * 64 + nt * 16 + lid) * LD + ks * 32 + quad * 8);
            acc2[0][nt] = __builtin_amdgcn_mfma_f32_16x16x32_bf16(a0, bf, acc2[0][nt], 0, 0, 0);
            acc2[1][nt] = __builtin_amdgcn_mfma_f32_16x16x32_bf16(a1, bf, acc2[1][nt], 0, 0, 0);
        }
    }

    if (outFp8) {
#pragma unroll
        for (int mt = 0; mt < 2; ++mt) {
#pragma unroll
            for (int nt = 0; nt < 4; ++nt) {
                int mbase = row0 + mw * 32 + mt * 16 + quad * 4;
                int n = nw * 64 + nt * 16 + lid;
                f32x4 v = acc2[mt][nt];
#pragma unroll
                for (int r = 0; r < 4; ++r) {
                    int row = mbase + r;
                    if (row < N) {
                        unsigned int p = (unsigned int)__builtin_amdgcn_cvt_pk_fp8_f32(v[r], 0.f, 0, false);
                        Hg8[(size_t)row * 128 + n] = (unsigned char)(p & 0xFF);
                    }
                }
            }
        }
    } else {
        // fused mean-pool: reduce this tile's rows into per-graph column sums
        __syncthreads();   // all waves done reading Xl/Wl before reuse of LDS timing
        int gmin = bgr[0];
        int last = 63;
        while (bgr[last] < 0) --last;   // only final block has invalid tail rows
        int gmax = bgr[last];
        for (int g = gmin; g <= gmax; ++g) {
            if (tid < 128) lsum[tid] = 0.f;
            __syncthreads();
#pragma unroll
            for (int mt = 0; mt < 2; ++mt) {
#pragma unroll
                for (int nt = 0; nt < 4; ++nt) {
                    int lrow = mw * 32 + mt * 16 + quad * 4;
                    int col  = nw * 64 + nt * 16 + lid;
                    f32x4 v = acc2[mt][nt];
#pragma unroll
                    for (int r = 0; r < 4; ++r) {
                        if (bgr[lrow + r] == g) atomicAdd(&lsum[col], v[r]);
                    }
                }
            }
            __syncthreads();
            if (tid < 128) atomicAdd(&gsum[g * C + tid], lsum[tid]);
            __syncthreads();
        }
    }
}

// ---------------- head: out[g] = (gsum[g]/cnt) @ Wl + bl ----------------

__global__ __launch_bounds__(64) void head_kernel(const float* __restrict__ gsum,
                                                  const int* __restrict__ gcnt,
                                                  const float* __restrict__ Wl,
                                                  const float* __restrict__ bl,
                                                  float* __restrict__ out) {
    int g = blockIdx.x;
    int t = threadIdx.x;   // 0..63
    __shared__ float pooled[C];
    float inv = 1.0f / (float)max(gcnt[g], 1);
    pooled[t]      = gsum[g * C + t] * inv;
    pooled[t + 64] = gsum[g * C + 64 + t] * inv;
    __syncthreads();
    float o = bl[t];
#pragma unroll 4
    for (int k = 0; k < C; ++k) o += pooled[k] * Wl[k * OC + t];
    out[g * OC + t] = o;
}

// ---------------- launch ----------------

extern "C" void kernel_launch(void* const* d_in, const int* in_sizes, int n_in,
                              void* d_out, int out_size, void* d_ws, size_t ws_size,
                              hipStream_t stream) {
    const float* x    = (const float*)d_in[0];
    const int*   ei   = (const int*)d_in[1];   // [2,E]
    const int*   bat  = (const int*)d_in[2];
    const float* W1a  = (const float*)d_in[3];
    const float* b1a  = (const float*)d_in[4];
    const float* W1b  = (const float*)d_in[5];
    const float* b1b  = (const float*)d_in[6];
    const float* W2a  = (const float*)d_in[7];
    const float* b2a  = (const float*)d_in[8];
    const float* W2b  = (const float*)d_in[9];
    const float* b2b  = (const float*)d_in[10];
    const float* Wl   = (const float*)d_in[11];
    const float* bl   = (const float*)d_in[12];
    float*       out  = (float*)d_out;

    // workspace: [cursor N][gsum G*C][gcnt G] (one memset) [ell][wt][x8][h8][y]
    int*   cursor  = (int*)d_ws;                          // N (ends as degree)
    float* gsum    = (float*)(cursor + N);                // G*C
    int*   gcnt    = (int*)(gsum + G * C);                // G
    unsigned short* ell = (unsigned short*)(gcnt + G);    // N*D ushort column-major
    unsigned short* wt  = ell + (size_t)N * D;            // 4*16384 bf16
    unsigned char*  x8  = (unsigned char*)(wt + 4 * 16384); // N*128 fp8
    unsigned char*  h8  = x8 + (size_t)N * 128;           // N*128 fp8
    unsigned short* y   = (unsigned short*)(h8 + (size_t)N * 128);  // (N+64)*128 bf16

    const unsigned short* wt1a = wt;
    const unsigned short* wt1b = wt + 16384;
    const unsigned short* wt2a = wt + 2 * 16384;
    const unsigned short* wt2b = wt + 3 * 16384;

    const int* src = ei;
    const int* dst = ei + E;

    hipMemsetAsync(cursor, 0, (size_t)(N + G * C + G) * sizeof(int), stream);

    int tb = (E / 4 + 255) / 256;   // 782 blocks, 4 edges/thread
    ell_build_kernel<<<tb, 256, 0, stream>>>(src, dst, cursor, ell);

    // 256 blocks for weights + 3125 for x->fp8
    prep_kernel<<<256 + (N * C / 8 + 255) / 256, 256, 0, stream>>>(W1a, W1b, W2a, W2b, x,
                                                                   wt, (unsigned int*)x8);

    int ab = (N + 31) / 32;   // 1563
    int mb = (N + 63) / 64;   // 782

    // conv1: gather x8 -> y; MLP y -> h8 (fp8 table for conv2)
    aggregate_kernel<<<ab, 256, 0, stream>>>(x8, cursor, ell, y);
    mlp_kernel<<<mb, 256, 0, stream>>>(y, wt1a, b1a, wt1b, b1b, h8, nullptr, nullptr, nullptr, 1);

    // conv2: gather h8 -> y; MLP y -> fused per-graph pool sums
    aggregate_kernel<<<ab, 256, 0, stream>>>(h8, cursor, ell, y);
    mlp_kernel<<<mb, 256, 0, stream>>>(y, wt2a, b2a, wt2b, b2b, nullptr, bat, gsum, gcnt, 0);

    head_kernel<<<G, 64, 0, stream>>>(gsum, gcnt, Wl, bl, out);
}

// Round 12
// 237.146 us; speedup vs baseline: 1.3806x; 1.3806x over previous
//
#include <hip/hip_runtime.h>

// Problem constants (from reference)
constexpr int N  = 50000;   // nodes
constexpr int E  = 800000;  // edges
constexpr int C  = 128;     // feature dim (IN_C == HID)
constexpr int G  = 256;     // graphs
constexpr int OC = 64;      // out channels
constexpr int D  = 64;      // ELL padded degree (Poisson(16): P(deg>=64) ~ 1e-20)

constexpr int TB = (E / 4 + 255) / 256;        // 782 ELL-build blocks
constexpr int WB = 256;                        // weight-prep blocks
constexpr int XB = (N * C / 8 + 255) / 256;    // 3125 x->fp8 blocks

typedef __attribute__((ext_vector_type(8))) short short8;
typedef __attribute__((ext_vector_type(4))) float f32x4;
typedef __attribute__((ext_vector_type(2))) float f32x2;

__device__ __forceinline__ unsigned int au(float f) { return __float_as_uint(f); }

__device__ __forceinline__ unsigned short f2bf(float f) {
    unsigned int u = au(f);
    u += 0x7fffu + ((u >> 16) & 1u);   // round-to-nearest-even
    return (unsigned short)(u >> 16);
}
// pack two floats to bf16x2 with round-half-up (cheap, bias negligible)
__device__ __forceinline__ unsigned int pack_bf16(float lo, float hi) {
    return ((au(hi) + 0x8000u) & 0xFFFF0000u) | ((au(lo) + 0x8000u) >> 16);
}

// decode 16 fp8(e4m3) in uint4 -> accumulate into 8 float2 (HW converts, pk adds)
__device__ __forceinline__ void acc16(f32x2* a, uint4 v) {
    a[0] += __builtin_amdgcn_cvt_pk_f32_fp8((int)v.x, false);
    a[1] += __builtin_amdgcn_cvt_pk_f32_fp8((int)v.x, true);
    a[2] += __builtin_amdgcn_cvt_pk_f32_fp8((int)v.y, false);
    a[3] += __builtin_amdgcn_cvt_pk_f32_fp8((int)v.y, true);
    a[4] += __builtin_amdgcn_cvt_pk_f32_fp8((int)v.z, false);
    a[5] += __builtin_amdgcn_cvt_pk_f32_fp8((int)v.z, true);
    a[6] += __builtin_amdgcn_cvt_pk_f32_fp8((int)v.w, false);
    a[7] += __builtin_amdgcn_cvt_pk_f32_fp8((int)v.w, true);
}
__device__ __forceinline__ void set16(f32x2* a, uint4 v) {
    a[0] = __builtin_amdgcn_cvt_pk_f32_fp8((int)v.x, false);
    a[1] = __builtin_amdgcn_cvt_pk_f32_fp8((int)v.x, true);
    a[2] = __builtin_amdgcn_cvt_pk_f32_fp8((int)v.y, false);
    a[3] = __builtin_amdgcn_cvt_pk_f32_fp8((int)v.y, true);
    a[4] = __builtin_amdgcn_cvt_pk_f32_fp8((int)v.z, false);
    a[5] = __builtin_amdgcn_cvt_pk_f32_fp8((int)v.z, true);
    a[6] = __builtin_amdgcn_cvt_pk_f32_fp8((int)v.w, false);
    a[7] = __builtin_amdgcn_cvt_pk_f32_fp8((int)v.w, true);
}

// ---------------- fused build+prep: ELL scatter || weight transpose || x->fp8 ----------------
// ELL (latency/atomic-bound, 782 blocks) overlaps with BW-bound prep (3381 blocks):
// prep blocks fill CUs idled by the ELL scatter's memory latency.

__global__ __launch_bounds__(256) void build_prep_kernel(const int* __restrict__ src,
                                                         const int* __restrict__ dst,
                                                         int* __restrict__ cursor,
                                                         unsigned short* __restrict__ ell,
                                                         const float* __restrict__ W1a,
                                                         const float* __restrict__ W1b,
                                                         const float* __restrict__ W2a,
                                                         const float* __restrict__ W2b,
                                                         const float* __restrict__ x,
                                                         unsigned short* __restrict__ wt,
                                                         unsigned int* __restrict__ x8) {
    int b = blockIdx.x;
    if (b < TB) {
        // ELL build, column-major ell[p*N + dst]
        int t = b * 256 + threadIdx.x;
        int e0 = t * 4;
        if (e0 + 4 <= E) {
            int4 d4 = ((const int4*)dst)[t];
            int4 s4 = ((const int4*)src)[t];
            int p0 = atomicAdd(&cursor[d4.x], 1);
            int p1 = atomicAdd(&cursor[d4.y], 1);
            int p2 = atomicAdd(&cursor[d4.z], 1);
            int p3 = atomicAdd(&cursor[d4.w], 1);
            if (p0 < D) ell[(size_t)p0 * N + d4.x] = (unsigned short)s4.x;
            if (p1 < D) ell[(size_t)p1 * N + d4.y] = (unsigned short)s4.y;
            if (p2 < D) ell[(size_t)p2 * N + d4.z] = (unsigned short)s4.z;
            if (p3 < D) ell[(size_t)p3 * N + d4.w] = (unsigned short)s4.w;
        } else {
            for (int e = e0; e < E; ++e) {
                int d = dst[e];
                int p = atomicAdd(&cursor[d], 1);
                if (p < D) ell[(size_t)p * N + d] = (unsigned short)src[e];
            }
        }
    } else if (b < TB + WB) {
        // weights -> bf16 WT[n][k]
        const float* Ws[4] = {W1a, W1b, W2a, W2b};
        int idx = (b - TB) * 256 + threadIdx.x;   // < 65536
        int which = idx >> 14;
        int el    = idx & 16383;
        int n = el >> 7, k = el & 127;
        wt[idx] = f2bf(Ws[which][k * 128 + n]);
    } else {
        // x -> fp8 table
        int idx = (b - TB - WB) * 256 + threadIdx.x;   // < N*C/8 = 800000
        const float4* x4 = (const float4*)x;
        float4 v0 = x4[idx * 2];
        float4 v1 = x4[idx * 2 + 1];
        unsigned int lo = 0, hi = 0;
        lo = (unsigned int)__builtin_amdgcn_cvt_pk_fp8_f32(v0.x, v0.y, (int)lo, false);
        lo = (unsigned int)__builtin_amdgcn_cvt_pk_fp8_f32(v0.z, v0.w, (int)lo, true);
        hi = (unsigned int)__builtin_amdgcn_cvt_pk_fp8_f32(v1.x, v1.y, (int)hi, false);
        hi = (unsigned int)__builtin_amdgcn_cvt_pk_fp8_f32(v1.z, v1.w, (int)hi, true);
        ((uint2*)x8)[idx] = make_uint2(lo, hi);
    }
}

// ---------------- aggregate: Y[n] = F[n] + sum_nb F[j]  (fp8 in, bf16 out) ----------------
// Zero LDS, 8 lanes/node (uint4 = 16 fp8 ch each). Software-pipelined batch-8.

__global__ __launch_bounds__(256) void aggregate_kernel(const unsigned char* __restrict__ Fg,
                                                        const int* __restrict__ deg,
                                                        const unsigned short* __restrict__ ell,
                                                        unsigned short* __restrict__ Y) {
    int grp = threadIdx.x >> 3;   // 0..31
    int l   = threadIdx.x & 7;    // 0..7
    int n = blockIdx.x * 32 + grp;
    if (n >= N) return;
    const uint4* F16 = (const uint4*)Fg;
    f32x2 a[8];
    int dg = min(deg[n], D);
    const unsigned short* ecol = ell + n;   // slot p at ecol[p*N]
    set16(a, F16[(size_t)n * 8 + l]);       // self
    int j = 0;
    if (dg >= 8) {
        int i0 = ecol[0];
        int i1 = ecol[(size_t)1 * N];
        int i2 = ecol[(size_t)2 * N];
        int i3 = ecol[(size_t)3 * N];
        int i4 = ecol[(size_t)4 * N];
        int i5 = ecol[(size_t)5 * N];
        int i6 = ecol[(size_t)6 * N];
        int i7 = ecol[(size_t)7 * N];
        uint4 v0 = F16[(size_t)i0 * 8 + l];
        uint4 v1 = F16[(size_t)i1 * 8 + l];
        uint4 v2 = F16[(size_t)i2 * 8 + l];
        uint4 v3 = F16[(size_t)i3 * 8 + l];
        uint4 v4 = F16[(size_t)i4 * 8 + l];
        uint4 v5 = F16[(size_t)i5 * 8 + l];
        uint4 v6 = F16[(size_t)i6 * 8 + l];
        uint4 v7 = F16[(size_t)i7 * 8 + l];
        for (j = 8; j + 8 <= dg; j += 8) {
            int t0 = ecol[(size_t)(j + 0) * N];
            int t1 = ecol[(size_t)(j + 1) * N];
            int t2 = ecol[(size_t)(j + 2) * N];
            int t3 = ecol[(size_t)(j + 3) * N];
            int t4 = ecol[(size_t)(j + 4) * N];
            int t5 = ecol[(size_t)(j + 5) * N];
            int t6 = ecol[(size_t)(j + 6) * N];
            int t7 = ecol[(size_t)(j + 7) * N];
            uint4 w0 = F16[(size_t)t0 * 8 + l];
            uint4 w1 = F16[(size_t)t1 * 8 + l];
            uint4 w2 = F16[(size_t)t2 * 8 + l];
            uint4 w3 = F16[(size_t)t3 * 8 + l];
            uint4 w4 = F16[(size_t)t4 * 8 + l];
            uint4 w5 = F16[(size_t)t5 * 8 + l];
            uint4 w6 = F16[(size_t)t6 * 8 + l];
            uint4 w7 = F16[(size_t)t7 * 8 + l];
            // decode previous batch while w* are in flight
            acc16(a, v0); acc16(a, v1); acc16(a, v2); acc16(a, v3);
            acc16(a, v4); acc16(a, v5); acc16(a, v6); acc16(a, v7);
            v0 = w0; v1 = w1; v2 = w2; v3 = w3;
            v4 = w4; v5 = w5; v6 = w6; v7 = w7;
        }
        acc16(a, v0); acc16(a, v1); acc16(a, v2); acc16(a, v3);
        acc16(a, v4); acc16(a, v5); acc16(a, v6); acc16(a, v7);
    }
    for (; j < dg; ++j) {
        uint4 v = F16[(size_t)ecol[(size_t)j * N] * 8 + l];
        acc16(a, v);
    }
    uint4 o0, o1;
    o0.x = pack_bf16(a[0].x, a[0].y); o0.y = pack_bf16(a[1].x, a[1].y);
    o0.z = pack_bf16(a[2].x, a[2].y); o0.w = pack_bf16(a[3].x, a[3].y);
    o1.x = pack_bf16(a[4].x, a[4].y); o1.y = pack_bf16(a[5].x, a[5].y);
    o1.z = pack_bf16(a[6].x, a[6].y); o1.w = pack_bf16(a[7].x, a[7].y);
    uint4* yp = (uint4*)(Y + (size_t)n * 128 + l * 16);
    yp[0] = o0;
    yp[1] = o1;
}

// ---------------- MLP: H = relu(X@Wa + ba)@Wb + bb  (bf16 MFMA) ----------------
// Output fp8 table (conv1) or bf16 rows (conv2, for pooling).

__global__ __launch_bounds__(256) void mlp_kernel(const unsigned short* __restrict__ Xg,
                                                  const unsigned short* __restrict__ WaT,
                                                  const float* __restrict__ ba,
                                                  const unsigned short* __restrict__ WbT,
                                                  const float* __restrict__ bb,
                                                  unsigned char* __restrict__ Hg8,
                                                  unsigned short* __restrict__ Hgb,
                                                  int outFp8) {
    constexpr int LD = 136;  // padded row stride in halfs
    __shared__ short Xl[64 * LD];
    __shared__ short Wl[128 * LD];
    int tid  = threadIdx.x;
    int lane = tid & 63;
    int wave = tid >> 6;
    int row0 = blockIdx.x * 64;

    // stage X tile (y is padded past N rows, no guard needed)
    const short8* Xg8 = (const short8*)(Xg + (size_t)row0 * 128);
#pragma unroll
    for (int i = tid; i < 1024; i += 256) {
        int r = i >> 4, c = i & 15;
        *((short8*)(Xl + r * LD) + c) = Xg8[i];
    }
    const short8* Wa8 = (const short8*)WaT;
#pragma unroll
    for (int i = tid; i < 2048; i += 256) {
        int r = i >> 4, c = i & 15;
        *((short8*)(Wl + r * LD) + c) = Wa8[i];
    }

    int mw = wave >> 1, nw = wave & 1;
    int lid = lane & 15, quad = lane >> 4;

    f32x4 acc[2][4];
#pragma unroll
    for (int nt = 0; nt < 4; ++nt) {
        float b = ba[nw * 64 + nt * 16 + lid];
        acc[0][nt] = (f32x4){b, b, b, b};
        acc[1][nt] = (f32x4){b, b, b, b};
    }
    __syncthreads();

    // layer 1: T = relu(X @ Wa + ba)
#pragma unroll
    for (int ks = 0; ks < 4; ++ks) {
        short8 a0 = *(const short8*)(Xl + (mw * 32 + lid) * LD + ks * 32 + quad * 8);
        short8 a1 = *(const short8*)(Xl + (mw * 32 + 16 + lid) * LD + ks * 32 + quad * 8);
#pragma unroll
        for (int nt = 0; nt < 4; ++nt) {
            short8 bf = *(const short8*)(Wl + (nw * 64 + nt * 16 + lid) * LD + ks * 32 + quad * 8);
            acc[0][nt] = __builtin_amdgcn_mfma_f32_16x16x32_bf16(a0, bf, acc[0][nt], 0, 0, 0);
            acc[1][nt] = __builtin_amdgcn_mfma_f32_16x16x32_bf16(a1, bf, acc[1][nt], 0, 0, 0);
        }
    }
    __syncthreads();

    // write T (relu, bf16) over the X tile; D-frag: row = quad*4+r, col = lid
#pragma unroll
    for (int mt = 0; mt < 2; ++mt) {
#pragma unroll
        for (int nt = 0; nt < 4; ++nt) {
            int mbase = mw * 32 + mt * 16 + quad * 4;
            int n = nw * 64 + nt * 16 + lid;
            f32x4 v = acc[mt][nt];
#pragma unroll
            for (int r = 0; r < 4; ++r)
                Xl[(mbase + r) * LD + n] = (short)f2bf(fmaxf(v[r], 0.f));
        }
    }
    const short8* Wb8 = (const short8*)WbT;
#pragma unroll
    for (int i = tid; i < 2048; i += 256) {
        int r = i >> 4, c = i & 15;
        *((short8*)(Wl + r * LD) + c) = Wb8[i];
    }
    f32x4 acc2[2][4];
#pragma unroll
    for (int nt = 0; nt < 4; ++nt) {
        float b = bb[nw * 64 + nt * 16 + lid];
        acc2[0][nt] = (f32x4){b, b, b, b};
        acc2[1][nt] = (f32x4){b, b, b, b};
    }
    __syncthreads();

    // layer 2: H = T @ Wb + bb
#pragma unroll
    for (int ks = 0; ks < 4; ++ks) {
        short8 a0 = *(const short8*)(Xl + (mw * 32 + lid) * LD + ks * 32 + quad * 8);
        short8 a1 = *(const short8*)(Xl + (mw * 32 + 16 + lid) * LD + ks * 32 + quad * 8);
#pragma unroll
        for (int nt = 0; nt < 4; ++nt) {
            short8 bf = *(const short8*)(Wl + (nw * 64 + nt * 16 + lid) * LD + ks * 32 + quad * 8);
            acc2[0][nt] = __builtin_amdgcn_mfma_f32_16x16x32_bf16(a0, bf, acc2[0][nt], 0, 0, 0);
            acc2[1][nt] = __builtin_amdgcn_mfma_f32_16x16x32_bf16(a1, bf, acc2[1][nt], 0, 0, 0);
        }
    }

#pragma unroll
    for (int mt = 0; mt < 2; ++mt) {
#pragma unroll
        for (int nt = 0; nt < 4; ++nt) {
            int mbase = row0 + mw * 32 + mt * 16 + quad * 4;
            int n = nw * 64 + nt * 16 + lid;
            f32x4 v = acc2[mt][nt];
            if (outFp8) {
#pragma unroll
                for (int r = 0; r < 4; ++r) {
                    int row = mbase + r;
                    if (row < N) {
                        unsigned int p = (unsigned int)__builtin_amdgcn_cvt_pk_fp8_f32(v[r], 0.f, 0, false);
                        Hg8[(size_t)row * 128 + n] = (unsigned char)(p & 0xFF);
                    }
                }
            } else {
#pragma unroll
                for (int r = 0; r < 4; ++r) {
                    int row = mbase + r;
                    if (row < N) Hgb[(size_t)row * 128 + n] = f2bf(v[r]);
                }
            }
        }
    }
}

// ---------------- pool phase 1: 4 waves/block, 16 rows each, boundary flush ----------------

__global__ __launch_bounds__(256) void pool_partial_kernel(const unsigned short* __restrict__ H,
                                                           const int* __restrict__ batch,
                                                           float* __restrict__ gsum,
                                                           int* __restrict__ gcnt) {
    int tid = threadIdx.x;
    int w = tid >> 6;      // wave 0..3
    int l = tid & 63;      // lane: channels {2l, 2l+1}
    int r0 = blockIdx.x * 64 + w * 16;
    if (r0 >= N) return;
    int rend = min(r0 + 16, N);
    const unsigned int* H2 = (const unsigned int*)H;  // ushort2 per load
    int curg = batch[r0];
    int runstart = r0;
    float a0 = 0.f, a1 = 0.f;
    for (int r = r0; r < rend; ++r) {
        int g = batch[r];                 // wave-uniform broadcast load
        if (g != curg) {
            atomicAdd(&gsum[curg * C + 2 * l], a0);
            atomicAdd(&gsum[curg * C + 2 * l + 1], a1);
            if (l == 0) atomicAdd(&gcnt[curg], r - runstart);
            curg = g; runstart = r; a0 = 0.f; a1 = 0.f;
        }
        unsigned int v = H2[(size_t)r * 64 + l];
        a0 += __uint_as_float((v & 0xffffu) << 16);
        a1 += __uint_as_float(v & 0xffff0000u);
    }
    atomicAdd(&gsum[curg * C + 2 * l], a0);
    atomicAdd(&gsum[curg * C + 2 * l + 1], a1);
    if (l == 0) atomicAdd(&gcnt[curg], rend - runstart);
}

// ---------------- head: out[g] = (gsum[g]/cnt) @ Wl + bl ----------------

__global__ __launch_bounds__(64) void head_kernel(const float* __restrict__ gsum,
                                                  const int* __restrict__ gcnt,
                                                  const float* __restrict__ Wl,
                                                  const float* __restrict__ bl,
                                                  float* __restrict__ out) {
    int g = blockIdx.x;
    int t = threadIdx.x;   // 0..63
    __shared__ float pooled[C];
    float inv = 1.0f / (float)max(gcnt[g], 1);
    pooled[t]      = gsum[g * C + t] * inv;
    pooled[t + 64] = gsum[g * C + 64 + t] * inv;
    __syncthreads();
    float o = bl[t];
#pragma unroll 4
    for (int k = 0; k < C; ++k) o += pooled[k] * Wl[k * OC + t];
    out[g * OC + t] = o;
}

// ---------------- launch ----------------

extern "C" void kernel_launch(void* const* d_in, const int* in_sizes, int n_in,
                              void* d_out, int out_size, void* d_ws, size_t ws_size,
                              hipStream_t stream) {
    const float* x    = (const float*)d_in[0];
    const int*   ei   = (const int*)d_in[1];   // [2,E]
    const int*   bat  = (const int*)d_in[2];
    const float* W1a  = (const float*)d_in[3];
    const float* b1a  = (const float*)d_in[4];
    const float* W1b  = (const float*)d_in[5];
    const float* b1b  = (const float*)d_in[6];
    const float* W2a  = (const float*)d_in[7];
    const float* b2a  = (const float*)d_in[8];
    const float* W2b  = (const float*)d_in[9];
    const float* b2b  = (const float*)d_in[10];
    const float* Wl   = (const float*)d_in[11];
    const float* bl   = (const float*)d_in[12];
    float*       out  = (float*)d_out;

    // workspace: [cursor N][gsum G*C][gcnt G] (one memset) [ell][wt][x8][h8][y][hb]
    int*   cursor  = (int*)d_ws;                          // N (ends as degree)
    float* gsum    = (float*)(cursor + N);                // G*C
    int*   gcnt    = (int*)(gsum + G * C);                // G
    unsigned short* ell = (unsigned short*)(gcnt + G);    // N*D ushort column-major
    unsigned short* wt  = ell + (size_t)N * D;            // 4*16384 bf16
    unsigned char*  x8  = (unsigned char*)(wt + 4 * 16384); // N*128 fp8
    unsigned char*  h8  = x8 + (size_t)N * 128;           // N*128 fp8
    unsigned short* y   = (unsigned short*)(h8 + (size_t)N * 128);  // (N+64)*128 bf16
    unsigned short* hb  = y + (size_t)(N + 64) * 128;     // N*128 bf16

    const unsigned short* wt1a = wt;
    const unsigned short* wt1b = wt + 16384;
    const unsigned short* wt2a = wt + 2 * 16384;
    const unsigned short* wt2b = wt + 3 * 16384;

    const int* src = ei;
    const int* dst = ei + E;

    hipMemsetAsync(cursor, 0, (size_t)(N + G * C + G) * sizeof(int), stream);

    // fused: ELL build (TB blocks) + weight prep (WB) + x->fp8 (XB)
    build_prep_kernel<<<TB + WB + XB, 256, 0, stream>>>(src, dst, cursor, ell,
                                                        W1a, W1b, W2a, W2b, x,
                                                        wt, (unsigned int*)x8);

    int ab = (N + 31) / 32;   // 1563
    int mb = (N + 63) / 64;   // 782

    // conv1: gather x8 -> y; MLP y -> h8 (fp8 table for conv2)
    aggregate_kernel<<<ab, 256, 0, stream>>>(x8, cursor, ell, y);
    mlp_kernel<<<mb, 256, 0, stream>>>(y, wt1a, b1a, wt1b, b1b, h8, nullptr, 1);

    // conv2: gather h8 -> y; MLP y -> hb (bf16 for pooling)
    aggregate_kernel<<<ab, 256, 0, stream>>>(h8, cursor, ell, y);
    mlp_kernel<<<mb, 256, 0, stream>>>(y, wt2a, b2a, wt2b, b2b, nullptr, hb, 0);

    pool_partial_kernel<<<mb, 256, 0, stream>>>(hb, bat, gsum, gcnt);
    head_kernel<<<G, 64, 0, stream>>>(gsum, gcnt, Wl, bl, out);
}

// Round 13
// 221.038 us; speedup vs baseline: 1.4812x; 1.0729x over previous
//
#include <hip/hip_runtime.h>

// Problem constants (from reference)
constexpr int N  = 50000;   // nodes
constexpr int E  = 800000;  // edges
constexpr int C  = 128;     // feature dim (IN_C == HID)
constexpr int G  = 256;     // graphs
constexpr int OC = 64;      // out channels
constexpr int D  = 64;      // ELL padded degree (Poisson(16): P(deg>=64) ~ 1e-20)

constexpr int NBUCK = 196;     // 256-node buckets: bucket = dst >> 8 (max 49999>>8 = 195)
constexpr int BCAP  = 5120;    // bucket capacity (mean 4096, sigma ~64 -> 16 sigma head)
constexpr int EB = (E + 4095) / 4096;          // 196 edge-binning blocks (4096 edges each)
constexpr int WB = 256;                        // weight-prep blocks
constexpr int XB = (N * C / 8 + 255) / 256;    // 3125 x->fp8 blocks

typedef __attribute__((ext_vector_type(8))) short short8;
typedef __attribute__((ext_vector_type(4))) float f32x4;
typedef __attribute__((ext_vector_type(2))) float f32x2;

__device__ __forceinline__ unsigned int au(float f) { return __float_as_uint(f); }

__device__ __forceinline__ unsigned short f2bf(float f) {
    unsigned int u = au(f);
    u += 0x7fffu + ((u >> 16) & 1u);   // round-to-nearest-even
    return (unsigned short)(u >> 16);
}
// pack two floats to bf16x2 with round-half-up (cheap, bias negligible)
__device__ __forceinline__ unsigned int pack_bf16(float lo, float hi) {
    return ((au(hi) + 0x8000u) & 0xFFFF0000u) | ((au(lo) + 0x8000u) >> 16);
}

// decode 16 fp8(e4m3) in uint4 -> accumulate into 8 float2 (HW converts, pk adds)
__device__ __forceinline__ void acc16(f32x2* a, uint4 v) {
    a[0] += __builtin_amdgcn_cvt_pk_f32_fp8((int)v.x, false);
    a[1] += __builtin_amdgcn_cvt_pk_f32_fp8((int)v.x, true);
    a[2] += __builtin_amdgcn_cvt_pk_f32_fp8((int)v.y, false);
    a[3] += __builtin_amdgcn_cvt_pk_f32_fp8((int)v.y, true);
    a[4] += __builtin_amdgcn_cvt_pk_f32_fp8((int)v.z, false);
    a[5] += __builtin_amdgcn_cvt_pk_f32_fp8((int)v.z, true);
    a[6] += __builtin_amdgcn_cvt_pk_f32_fp8((int)v.w, false);
    a[7] += __builtin_amdgcn_cvt_pk_f32_fp8((int)v.w, true);
}
__device__ __forceinline__ void set16(f32x2* a, uint4 v) {
    a[0] = __builtin_amdgcn_cvt_pk_f32_fp8((int)v.x, false);
    a[1] = __builtin_amdgcn_cvt_pk_f32_fp8((int)v.x, true);
    a[2] = __builtin_amdgcn_cvt_pk_f32_fp8((int)v.y, false);
    a[3] = __builtin_amdgcn_cvt_pk_f32_fp8((int)v.y, true);
    a[4] = __builtin_amdgcn_cvt_pk_f32_fp8((int)v.z, false);
    a[5] = __builtin_amdgcn_cvt_pk_f32_fp8((int)v.z, true);
    a[6] = __builtin_amdgcn_cvt_pk_f32_fp8((int)v.w, false);
    a[7] = __builtin_amdgcn_cvt_pk_f32_fp8((int)v.w, true);
}

// ---------------- pass A: bin edges by dst-bucket  ||  weight/x prep ----------------
// Edge blocks: LDS histogram -> one global atomicAdd per (bucket,block) -> packed append.
// Appends form 196 quasi-sequential streams -> L2 accumulates full lines (no 1-line-per-edge).

__global__ __launch_bounds__(256) void build_prep_kernel(const int* __restrict__ src,
                                                         const int* __restrict__ dst,
                                                         int* __restrict__ bcount,
                                                         unsigned int* __restrict__ bucketbuf,
                                                         const float* __restrict__ W1a,
                                                         const float* __restrict__ W1b,
                                                         const float* __restrict__ W2a,
                                                         const float* __restrict__ W2b,
                                                         const float* __restrict__ x,
                                                         unsigned short* __restrict__ wt,
                                                         unsigned int* __restrict__ x8) {
    int b = blockIdx.x;
    if (b < EB) {
        __shared__ int lcount[NBUCK];
        __shared__ int lbase[NBUCK];
        __shared__ int lcur[NBUCK];
        int tid = threadIdx.x;
        for (int i = tid; i < NBUCK; i += 256) { lcount[i] = 0; lcur[i] = 0; }
        __syncthreads();
        int e0 = b * 4096;
        int sv[16], dv[16];
#pragma unroll
        for (int i = 0; i < 16; ++i) {
            int e = e0 + i * 256 + tid;
            if (e < E) {
                sv[i] = src[e];
                dv[i] = dst[e];
                atomicAdd(&lcount[dv[i] >> 8], 1);
            } else {
                dv[i] = -1;
            }
        }
        __syncthreads();
        if (tid < NBUCK) {
            int c = lcount[tid];
            lbase[tid] = (c > 0) ? atomicAdd(&bcount[tid], c) : 0;
        }
        __syncthreads();
#pragma unroll
        for (int i = 0; i < 16; ++i) {
            if (dv[i] >= 0) {
                int bk = dv[i] >> 8;
                int pos = lbase[bk] + atomicAdd(&lcur[bk], 1);
                if (pos < BCAP)
                    bucketbuf[(size_t)bk * BCAP + pos] =
                        ((unsigned int)sv[i] << 16) | (unsigned int)(dv[i] & 255);
            }
        }
    } else if (b < EB + WB) {
        // weights -> bf16 WT[n][k]
        const float* Ws[4] = {W1a, W1b, W2a, W2b};
        int idx = (b - EB) * 256 + threadIdx.x;   // < 65536
        int which = idx >> 14;
        int el    = idx & 16383;
        int n = el >> 7, k = el & 127;
        wt[idx] = f2bf(Ws[which][k * 128 + n]);
    } else {
        // x -> fp8 table
        int idx = (b - EB - WB) * 256 + threadIdx.x;   // < N*C/8 = 800000
        const float4* x4 = (const float4*)x;
        float4 v0 = x4[idx * 2];
        float4 v1 = x4[idx * 2 + 1];
        unsigned int lo = 0, hi = 0;
        lo = (unsigned int)__builtin_amdgcn_cvt_pk_fp8_f32(v0.x, v0.y, (int)lo, false);
        lo = (unsigned int)__builtin_amdgcn_cvt_pk_fp8_f32(v0.z, v0.w, (int)lo, true);
        hi = (unsigned int)__builtin_amdgcn_cvt_pk_fp8_f32(v1.x, v1.y, (int)hi, false);
        hi = (unsigned int)__builtin_amdgcn_cvt_pk_fp8_f32(v1.z, v1.w, (int)hi, true);
        ((uint2*)x8)[idx] = make_uint2(lo, hi);
    }
}

// ---------------- pass B: per-bucket ELL fill, LDS cursors ----------------
// One block per bucket. ELL writes confined to 64 x 512B segments (32 KB, one XCD's L2).
// Writes deg[] directly (no cursor memset needed).

__global__ __launch_bounds__(256) void bucket_fill_kernel(const int* __restrict__ bcount,
                                                          const unsigned int* __restrict__ bucketbuf,
                                                          unsigned short* __restrict__ ell,
                                                          int* __restrict__ deg) {
    __shared__ int lcur[256];
    int b = blockIdx.x;
    int tid = threadIdx.x;
    lcur[tid] = 0;
    __syncthreads();
    int cnt = min(bcount[b], BCAP);
    const unsigned int* buf = bucketbuf + (size_t)b * BCAP;
    int nbase = b << 8;
    for (int i = tid; i < cnt; i += 256) {
        unsigned int e = buf[i];
        int dlow = (int)(e & 255u);
        int s = (int)(e >> 16);
        int p = atomicAdd(&lcur[dlow], 1);
        if (p < D) ell[(size_t)p * N + nbase + dlow] = (unsigned short)s;
    }
    __syncthreads();
    int node = nbase + tid;
    if (node < N) deg[node] = lcur[tid];
}

// ---------------- aggregate: Y[n] = F[n] + sum_nb F[j]  (fp8 in, bf16 out) ----------------
// Zero LDS, 8 lanes/node (uint4 = 16 fp8 ch each). Software-pipelined batch-8.

__global__ __launch_bounds__(256) void aggregate_kernel(const unsigned char* __restrict__ Fg,
                                                        const int* __restrict__ deg,
                                                        const unsigned short* __restrict__ ell,
                                                        unsigned short* __restrict__ Y) {
    int grp = threadIdx.x >> 3;   // 0..31
    int l   = threadIdx.x & 7;    // 0..7
    int n = blockIdx.x * 32 + grp;
    if (n >= N) return;
    const uint4* F16 = (const uint4*)Fg;
    f32x2 a[8];
    int dg = min(deg[n], D);
    const unsigned short* ecol = ell + n;   // slot p at ecol[p*N]
    set16(a, F16[(size_t)n * 8 + l]);       // self
    int j = 0;
    if (dg >= 8) {
        int i0 = ecol[0];
        int i1 = ecol[(size_t)1 * N];
        int i2 = ecol[(size_t)2 * N];
        int i3 = ecol[(size_t)3 * N];
        int i4 = ecol[(size_t)4 * N];
        int i5 = ecol[(size_t)5 * N];
        int i6 = ecol[(size_t)6 * N];
        int i7 = ecol[(size_t)7 * N];
        uint4 v0 = F16[(size_t)i0 * 8 + l];
        uint4 v1 = F16[(size_t)i1 * 8 + l];
        uint4 v2 = F16[(size_t)i2 * 8 + l];
        uint4 v3 = F16[(size_t)i3 * 8 + l];
        uint4 v4 = F16[(size_t)i4 * 8 + l];
        uint4 v5 = F16[(size_t)i5 * 8 + l];
        uint4 v6 = F16[(size_t)i6 * 8 + l];
        uint4 v7 = F16[(size_t)i7 * 8 + l];
        for (j = 8; j + 8 <= dg; j += 8) {
            int t0 = ecol[(size_t)(j + 0) * N];
            int t1 = ecol[(size_t)(j + 1) * N];
            int t2 = ecol[(size_t)(j + 2) * N];
            int t3 = ecol[(size_t)(j + 3) * N];
            int t4 = ecol[(size_t)(j + 4) * N];
            int t5 = ecol[(size_t)(j + 5) * N];
            int t6 = ecol[(size_t)(j + 6) * N];
            int t7 = ecol[(size_t)(j + 7) * N];
            uint4 w0 = F16[(size_t)t0 * 8 + l];
            uint4 w1 = F16[(size_t)t1 * 8 + l];
            uint4 w2 = F16[(size_t)t2 * 8 + l];
            uint4 w3 = F16[(size_t)t3 * 8 + l];
            uint4 w4 = F16[(size_t)t4 * 8 + l];
            uint4 w5 = F16[(size_t)t5 * 8 + l];
            uint4 w6 = F16[(size_t)t6 * 8 + l];
            uint4 w7 = F16[(size_t)t7 * 8 + l];
            // decode previous batch while w* are in flight
            acc16(a, v0); acc16(a, v1); acc16(a, v2); acc16(a, v3);
            acc16(a, v4); acc16(a, v5); acc16(a, v6); acc16(a, v7);
            v0 = w0; v1 = w1; v2 = w2; v3 = w3;
            v4 = w4; v5 = w5; v6 = w6; v7 = w7;
        }
        acc16(a, v0); acc16(a, v1); acc16(a, v2); acc16(a, v3);
        acc16(a, v4); acc16(a, v5); acc16(a, v6); acc16(a, v7);
    }
    for (; j < dg; ++j) {
        uint4 v = F16[(size_t)ecol[(size_t)j * N] * 8 + l];
        acc16(a, v);
    }
    uint4 o0, o1;
    o0.x = pack_bf16(a[0].x, a[0].y); o0.y = pack_bf16(a[1].x, a[1].y);
    o0.z = pack_bf16(a[2].x, a[2].y); o0.w = pack_bf16(a[3].x, a[3].y);
    o1.x = pack_bf16(a[4].x, a[4].y); o1.y = pack_bf16(a[5].x, a[5].y);
    o1.z = pack_bf16(a[6].x, a[6].y); o1.w = pack_bf16(a[7].x, a[7].y);
    uint4* yp = (uint4*)(Y + (size_t)n * 128 + l * 16);
    yp[0] = o0;
    yp[1] = o1;
}

// ---------------- MLP: H = relu(X@Wa + ba)@Wb + bb  (bf16 MFMA) ----------------
// Output fp8 table (conv1) or bf16 rows (conv2, for pooling).

__global__ __launch_bounds__(256) void mlp_kernel(const unsigned short* __restrict__ Xg,
                                                  const unsigned short* __restrict__ WaT,
                                                  const float* __restrict__ ba,
                                                  const unsigned short* __restrict__ WbT,
                                                  const float* __restrict__ bb,
                                                  unsigned char* __restrict__ Hg8,
                                                  unsigned short* __restrict__ Hgb,
                                                  int outFp8) {
    constexpr int LD = 136;  // padded row stride in halfs
    __shared__ short Xl[64 * LD];
    __shared__ short Wl[128 * LD];
    int tid  = threadIdx.x;
    int lane = tid & 63;
    int wave = tid >> 6;
    int row0 = blockIdx.x * 64;

    // stage X tile (y is padded past N rows, no guard needed)
    const short8* Xg8 = (const short8*)(Xg + (size_t)row0 * 128);
#pragma unroll
    for (int i = tid; i < 1024; i += 256) {
        int r = i >> 4, c = i & 15;
        *((short8*)(Xl + r * LD) + c) = Xg8[i];
    }
    const short8* Wa8 = (const short8*)WaT;
#pragma unroll
    for (int i = tid; i < 2048; i += 256) {
        int r = i >> 4, c = i & 15;
        *((short8*)(Wl + r * LD) + c) = Wa8[i];
    }

    int mw = wave >> 1, nw = wave & 1;
    int lid = lane & 15, quad = lane >> 4;

    f32x4 acc[2][4];
#pragma unroll
    for (int nt = 0; nt < 4; ++nt) {
        float b = ba[nw * 64 + nt * 16 + lid];
        acc[0][nt] = (f32x4){b, b, b, b};
        acc[1][nt] = (f32x4){b, b, b, b};
    }
    __syncthreads();

    // layer 1: T = relu(X @ Wa + ba)
#pragma unroll
    for (int ks = 0; ks < 4; ++ks) {
        short8 a0 = *(const short8*)(Xl + (mw * 32 + lid) * LD + ks * 32 + quad * 8);
        short8 a1 = *(const short8*)(Xl + (mw * 32 + 16 + lid) * LD + ks * 32 + quad * 8);
#pragma unroll
        for (int nt = 0; nt < 4; ++nt) {
            short8 bf = *(const short8*)(Wl + (nw * 64 + nt * 16 + lid) * LD + ks * 32 + quad * 8);
            acc[0][nt] = __builtin_amdgcn_mfma_f32_16x16x32_bf16(a0, bf, acc[0][nt], 0, 0, 0);
            acc[1][nt] = __builtin_amdgcn_mfma_f32_16x16x32_bf16(a1, bf, acc[1][nt], 0, 0, 0);
        }
    }
    __syncthreads();

    // write T (relu, bf16) over the X tile; D-frag: row = quad*4+r, col = lid
#pragma unroll
    for (int mt = 0; mt < 2; ++mt) {
#pragma unroll
        for (int nt = 0; nt < 4; ++nt) {
            int mbase = mw * 32 + mt * 16 + quad * 4;
            int n = nw * 64 + nt * 16 + lid;
            f32x4 v = acc[mt][nt];
#pragma unroll
            for (int r = 0; r < 4; ++r)
                Xl[(mbase + r) * LD + n] = (short)f2bf(fmaxf(v[r], 0.f));
        }
    }
    const short8* Wb8 = (const short8*)WbT;
#pragma unroll
    for (int i = tid; i < 2048; i += 256) {
        int r = i >> 4, c = i & 15;
        *((short8*)(Wl + r * LD) + c) = Wb8[i];
    }
    f32x4 acc2[2][4];
#pragma unroll
    for (int nt = 0; nt < 4; ++nt) {
        float b = bb[nw * 64 + nt * 16 + lid];
        acc2[0][nt] = (f32x4){b, b, b, b};
        acc2[1][nt] = (f32x4){b, b, b, b};
    }
    __syncthreads();

    // layer 2: H = T @ Wb + bb
#pragma unroll
    for (int ks = 0; ks < 4; ++ks) {
        short8 a0 = *(const short8*)(Xl + (mw * 32 + lid) * LD + ks * 32 + quad * 8);
        short8 a1 = *(const short8*)(Xl + (mw * 32 + 16 + lid) * LD + ks * 32 + quad * 8);
#pragma unroll
        for (int nt = 0; nt < 4; ++nt) {
            short8 bf = *(const short8*)(Wl + (nw * 64 + nt * 16 + lid) * LD + ks * 32 + quad * 8);
            acc2[0][nt] = __builtin_amdgcn_mfma_f32_16x16x32_bf16(a0, bf, acc2[0][nt], 0, 0, 0);
            acc2[1][nt] = __builtin_amdgcn_mfma_f32_16x16x32_bf16(a1, bf, acc2[1][nt], 0, 0, 0);
        }
    }

#pragma unroll
    for (int mt = 0; mt < 2; ++mt) {
#pragma unroll
        for (int nt = 0; nt < 4; ++nt) {
            int mbase = row0 + mw * 32 + mt * 16 + quad * 4;
            int n = nw * 64 + nt * 16 + lid;
            f32x4 v = acc2[mt][nt];
            if (outFp8) {
#pragma unroll
                for (int r = 0; r < 4; ++r) {
                    int row = mbase + r;
                    if (row < N) {
                        unsigned int p = (unsigned int)__builtin_amdgcn_cvt_pk_fp8_f32(v[r], 0.f, 0, false);
                        Hg8[(size_t)row * 128 + n] = (unsigned char)(p & 0xFF);
                    }
                }
            } else {
#pragma unroll
                for (int r = 0; r < 4; ++r) {
                    int row = mbase + r;
                    if (row < N) Hgb[(size_t)row * 128 + n] = f2bf(v[r]);
                }
            }
        }
    }
}

// ---------------- pool phase 1: 4 waves/block, 16 rows each, boundary flush ----------------

__global__ __launch_bounds__(256) void pool_partial_kernel(const unsigned short* __restrict__ H,
                                                           const int* __restrict__ batch,
                                                           float* __restrict__ gsum,
                                                           int* __restrict__ gcnt) {
    int tid = threadIdx.x;
    int w = tid >> 6;      // wave 0..3
    int l = tid & 63;      // lane: channels {2l, 2l+1}
    int r0 = blockIdx.x * 64 + w * 16;
    if (r0 >= N) return;
    int rend = min(r0 + 16, N);
    const unsigned int* H2 = (const unsigned int*)H;  // ushort2 per load
    int curg = batch[r0];
    int runstart = r0;
    float a0 = 0.f, a1 = 0.f;
    for (int r = r0; r < rend; ++r) {
        int g = batch[r];                 // wave-uniform broadcast load
        if (g != curg) {
            atomicAdd(&gsum[curg * C + 2 * l], a0);
            atomicAdd(&gsum[curg * C + 2 * l + 1], a1);
            if (l == 0) atomicAdd(&gcnt[curg], r - runstart);
            curg = g; runstart = r; a0 = 0.f; a1 = 0.f;
        }
        unsigned int v = H2[(size_t)r * 64 + l];
        a0 += __uint_as_float((v & 0xffffu) << 16);
        a1 += __uint_as_float(v & 0xffff0000u);
    }
    atomicAdd(&gsum[curg * C + 2 * l], a0);
    atomicAdd(&gsum[curg * C + 2 * l + 1], a1);
    if (l == 0) atomicAdd(&gcnt[curg], rend - runstart);
}

// ---------------- head: out[g] = (gsum[g]/cnt) @ Wl + bl ----------------

__global__ __launch_bounds__(64) void head_kernel(const float* __restrict__ gsum,
                                                  const int* __restrict__ gcnt,
                                                  const float* __restrict__ Wl,
                                                  const float* __restrict__ bl,
                                                  float* __restrict__ out) {
    int g = blockIdx.x;
    int t = threadIdx.x;   // 0..63
    __shared__ float pooled[C];
    float inv = 1.0f / (float)max(gcnt[g], 1);
    pooled[t]      = gsum[g * C + t] * inv;
    pooled[t + 64] = gsum[g * C + 64 + t] * inv;
    __syncthreads();
    float o = bl[t];
#pragma unroll 4
    for (int k = 0; k < C; ++k) o += pooled[k] * Wl[k * OC + t];
    out[g * OC + t] = o;
}

// ---------------- launch ----------------

extern "C" void kernel_launch(void* const* d_in, const int* in_sizes, int n_in,
                              void* d_out, int out_size, void* d_ws, size_t ws_size,
                              hipStream_t stream) {
    const float* x    = (const float*)d_in[0];
    const int*   ei   = (const int*)d_in[1];   // [2,E]
    const int*   bat  = (const int*)d_in[2];
    const float* W1a  = (const float*)d_in[3];
    const float* b1a  = (const float*)d_in[4];
    const float* W1b  = (const float*)d_in[5];
    const float* b1b  = (const float*)d_in[6];
    const float* W2a  = (const float*)d_in[7];
    const float* b2a  = (const float*)d_in[8];
    const float* W2b  = (const float*)d_in[9];
    const float* b2b  = (const float*)d_in[10];
    const float* Wl   = (const float*)d_in[11];
    const float* bl   = (const float*)d_in[12];
    float*       out  = (float*)d_out;

    // workspace: [gsum G*C][gcnt G][bcount NBUCK] <- one memset
    //            [deg N][bucketbuf NBUCK*BCAP][ell][wt][x8][h8][y][hb]
    float* gsum    = (float*)d_ws;                        // G*C
    int*   gcnt    = (int*)(gsum + G * C);                // G
    int*   bcount  = gcnt + G;                            // NBUCK
    int*   deg     = bcount + NBUCK;                      // N (written by bucket_fill)
    unsigned int* bucketbuf = (unsigned int*)(deg + N);   // NBUCK*BCAP (4 MB)
    unsigned short* ell = (unsigned short*)(bucketbuf + (size_t)NBUCK * BCAP);  // N*D
    unsigned short* wt  = ell + (size_t)N * D;            // 4*16384 bf16
    unsigned char*  x8  = (unsigned char*)(wt + 4 * 16384); // N*128 fp8
    unsigned char*  h8  = x8 + (size_t)N * 128;           // N*128 fp8
    unsigned short* y   = (unsigned short*)(h8 + (size_t)N * 128);  // (N+64)*128 bf16
    unsigned short* hb  = y + (size_t)(N + 64) * 128;     // N*128 bf16

    const unsigned short* wt1a = wt;
    const unsigned short* wt1b = wt + 16384;
    const unsigned short* wt2a = wt + 2 * 16384;
    const unsigned short* wt2b = wt + 3 * 16384;

    const int* src = ei;
    const int* dst = ei + E;

    hipMemsetAsync(gsum, 0, (size_t)(G * C + G + NBUCK) * sizeof(int), stream);

    // pass A: edge binning (EB blocks) + weight prep (WB) + x->fp8 (XB)
    build_prep_kernel<<<EB + WB + XB, 256, 0, stream>>>(src, dst, bcount, bucketbuf,
                                                        W1a, W1b, W2a, W2b, x,
                                                        wt, (unsigned int*)x8);
    // pass B: per-bucket ELL fill (LDS cursors), writes deg
    bucket_fill_kernel<<<NBUCK, 256, 0, stream>>>(bcount, bucketbuf, ell, deg);

    int ab = (N + 31) / 32;   // 1563
    int mb = (N + 63) / 64;   // 782

    // conv1: gather x8 -> y; MLP y -> h8 (fp8 table for conv2)
    aggregate_kernel<<<ab, 256, 0, stream>>>(x8, deg, ell, y);
    mlp_kernel<<<mb, 256, 0, stream>>>(y, wt1a, b1a, wt1b, b1b, h8, nullptr, 1);

    // conv2: gather h8 -> y; MLP y -> hb (bf16 for pooling)
    aggregate_kernel<<<ab, 256, 0, stream>>>(h8, deg, ell, y);
    mlp_kernel<<<mb, 256, 0, stream>>>(y, wt2a, b2a, wt2b, b2b, nullptr, hb, 0);

    pool_partial_kernel<<<mb, 256, 0, stream>>>(hb, bat, gsum, gcnt);
    head_kernel<<<G, 64, 0, stream>>>(gsum, gcnt, Wl, bl, out);
}